// Round 3
// baseline (5704.453 us; speedup 1.0000x reference)
//
// R14: deterministic XCD affinity, zero new correctness dependencies.
// R12/R13 post-mortem: bit-identical absmax 2.05e-2 + fast tests = scans
// NO-OP'd (all-zero out; error = max|ref|). The s_getreg XCC_ID claim yielded
// no claimers -> every block exited. Fix: drop XCC_ID entirely. Launch 256
// blocks; HW maps blockIdx -> XCD (b % 8) (same mapping T1 swizzle uses).
// Blocks b&7==0 = forward (XCD0), b&7==1 = backward (XCD1), cblk=b>>3; others
// exit. All 256 co-resident (1 block/CU) -> no deadlock under ANY mapping.
// Scan body is bit-identical to proven R11 (AGENT ring/flag ops, plain staged
// loads, __syncthreads step-end): placement is perf-only (G16). Win: plain
// staging loads now hit the home XCD's L2 (writer + 31 readers co-located);
// FETCH_SIZE drop is the placement evidence. Store-drain/flag stay LLC scope
// this round (correct under any placement); they're the next target.
#include <hip/hip_runtime.h>
#include <hip/hip_fp16.h>
#include <math.h>

#define NB   64
#define NS   256
#define ND   300
#define NDP  320
#define NH   512
#define N4H  2048

typedef _Float16 half8_t __attribute__((ext_vector_type(8)));
typedef float    f32x4_t __attribute__((ext_vector_type(4)));

// ---------- embedding: gather + fp16 convert + zero-pad K to 320 ----------
__global__ void embed_f16_kernel(const int* __restrict__ text,
                                 const float* __restrict__ emb,
                                 _Float16* __restrict__ x) {
  int idx = blockIdx.x * 256 + threadIdx.x;
  const int total = NB * NS * NDP;
  for (; idx < total; idx += gridDim.x * 256) {
    int bs = idx / NDP;
    int d  = idx - bs * NDP;
    x[idx] = (d < ND) ? (_Float16)emb[(size_t)text[bs] * ND + d] : (_Float16)0.f;
  }
}

// ---------- MFMA GEMM with in-LDS weight transpose (unchanged from R6) ----------
__global__ __launch_bounds__(256) void gemm_mfma_kernel(
    const _Float16* __restrict__ A, const float* __restrict__ W,
    const float* __restrict__ bias, __half* __restrict__ C,
    int M, int N, int K, int Kw) {
  __shared__ __align__(16) _Float16 as[128][40];
  __shared__ __align__(16) _Float16 ws16[128][40];
  __shared__ __align__(16) float    ws32[32][132];
  const int t = threadIdx.x;
  const int w = t >> 6;
  const int l = t & 63;
  const int lane16 = l & 15;
  const int kq = l >> 4;
  const int bm = blockIdx.y * 128;
  const int bn = blockIdx.x * 128;
  const int lr  = t >> 2;
  const int lsg = t & 3;
  const int wk  = t >> 3;
  const int wns = t & 7;
  const int rn  = t >> 1;
  const int rk0 = (t & 1) * 2;

  f32x4_t acc[2][8];
#pragma unroll
  for (int i = 0; i < 2; i++)
#pragma unroll
    for (int j = 0; j < 8; j++) acc[i][j] = (f32x4_t){0.f, 0.f, 0.f, 0.f};

  for (int k0 = 0; k0 < K; k0 += 32) {
#pragma unroll
    for (int h = 0; h < 2; h++) {
      int m = h * 64 + lr;
      *(uint4*)&as[m][lsg * 8] = *(const uint4*)(A + (size_t)(bm + m) * K + k0 + lsg * 8);
    }
    if (k0 + wk < Kw) {
#pragma unroll
      for (int i = 0; i < 4; i++)
        *(float4*)&ws32[wk][wns * 16 + i * 4] =
            *(const float4*)(W + (size_t)(k0 + wk) * N + bn + wns * 16 + i * 4);
    } else {
#pragma unroll
      for (int i = 0; i < 4; i++)
        *(float4*)&ws32[wk][wns * 16 + i * 4] = make_float4(0.f, 0.f, 0.f, 0.f);
    }
    __syncthreads();
#pragma unroll
    for (int g = 0; g < 2; g++) {
      int kqq = rk0 + g;
      half8_t hv;
#pragma unroll
      for (int jj = 0; jj < 8; jj++) hv[jj] = (_Float16)ws32[kqq * 8 + jj][rn];
      *(half8_t*)&ws16[rn][kqq * 8] = hv;
    }
    __syncthreads();
    half8_t afrag[2];
#pragma unroll
    for (int i = 0; i < 2; i++)
      afrag[i] = *(const half8_t*)&as[w * 32 + i * 16 + lane16][kq * 8];
#pragma unroll
    for (int j = 0; j < 8; j++) {
      half8_t bfrag = *(const half8_t*)&ws16[j * 16 + lane16][kq * 8];
#pragma unroll
      for (int i = 0; i < 2; i++)
        acc[i][j] = __builtin_amdgcn_mfma_f32_16x16x32_f16(afrag[i], bfrag, acc[i][j], 0, 0, 0);
    }
    __syncthreads();
  }
#pragma unroll
  for (int j = 0; j < 8; j++) {
    int col = bn + j * 16 + lane16;
    float bv = bias[col];
#pragma unroll
    for (int i = 0; i < 2; i++) {
      int rbase = bm + w * 32 + i * 16 + kq * 4;
#pragma unroll
      for (int r = 0; r < 4; r++)
        C[(size_t)(rbase + r) * N + col] = __float2half(acc[i][j][r] + bv);
    }
  }
}

// ---------- persistent bi-LSTM scan: R11 protocol + deterministic placement ----
// Grid MUST be 256 x 256thr. Block b participates iff (b&7) < 2:
// dir = b&7 (0=fwd -> XCD0 under b%8 round-robin, 1=bwd -> XCD1), cblk = b>>3.
// Owns h-cols [cblk*16,+16) (64 z-cols). ring slot tt holds h at time tt.
// Writes: relaxed AGENT 8B write-through (LLC-visible; line also lands in the
// writer's L2 -> co-located readers' plain loads hit local L2). Reads: plain
// cached uint4 (fresh lines: each ring line is written once, read once, and
// L1/L2 are invalidated at dispatch start). Barrier: flag[dir*32+cblk] = steps
// completed (monotonic, AGENT); wave0 polls all 32 flags in one load.
__global__ __launch_bounds__(256, 1) void scan_ring_kernel(
    const __half* __restrict__ xzf, const __half* __restrict__ xzb,
    const float* __restrict__ Uf, const float* __restrict__ Ub,
    const int* __restrict__ text,
    __half* ring,
    int* flags, int* abortf,
    float* __restrict__ hT_out) {
  __shared__ __align__(16) _Float16 s_h[64 * 512];   // 64KB h tile, XOR swizzle
  __shared__ __align__(16) float    s_z[64 * 68];    // 17.4KB z
  __shared__ int s_brk;

  const int t  = threadIdx.x;
  const int b  = blockIdx.x;
  const int grp = b & 7;
  if (grp >= 2) return;                // blocks on XCD2..7: exit immediately
  const int dir  = grp;
  const int cblk = b >> 3;             // 0..31
  const int hc0  = cblk * 16;
  const __half* xz = dir ? xzb : xzf;
  const float* U = dir ? Ub : Uf;
  int* myflags = flags + dir * 32;

  const int w    = t >> 6;          // wave = m-tile (rows w*16..w*16+16)
  const int lane = t & 63;
  const int l16  = lane & 15;
  const int quad = lane >> 4;

  // persistent U B-frags: ufrag[kt][nt][jj] = U[kt*32+quad*8+jj][nt*512+hc0+l16]
  half8_t ufrag[16][4];
#pragma unroll
  for (int nt = 0; nt < 4; nt++) {
    int col = nt * NH + hc0 + l16;
#pragma unroll
    for (int kt = 0; kt < 16; kt++)
#pragma unroll
      for (int jj = 0; jj < 8; jj++)
        ufrag[kt][nt][jj] = (_Float16)U[(size_t)(kt * 32 + quad * 8 + jj) * N4H + col];
  }

  // LSTM state: thread owns row = t>>2, cols jb..jb+3 (jb = (t&3)*4)
  const int srow = t >> 2;
  const int jb   = (t & 3) * 4;
  const int row0 = w * 16 + quad * 4;
  float c_st[4] = {0.f, 0.f, 0.f, 0.f}, h_st[4] = {0.f, 0.f, 0.f, 0.f};

  // xz prefetch registers (16 scalars per thread, step-s values)
  __half xzr[16];
  {
    int tt0 = dir ? (NS - 1) : 0;
#pragma unroll
    for (int nt = 0; nt < 4; nt++)
#pragma unroll
      for (int r4 = 0; r4 < 4; r4++)
        xzr[nt * 4 + r4] = xz[((size_t)(row0 + r4) * NS + tt0) * N4H + nt * NH + hc0 + l16];
  }

  for (int s = 0; s < NS; s++) {
    const int tt = dir ? (NS - 1 - s) : s;
    f32x4_t acc[4] = {{0.f,0.f,0.f,0.f},{0.f,0.f,0.f,0.f},{0.f,0.f,0.f,0.f},{0.f,0.f,0.f,0.f}};

    if (s > 0) {
      const int ttp = dir ? (tt + 1) : (tt - 1);   // slot holding h(s-1)
      // stage h(s-1): 64 rows x 512 fp16 via plain cached uint4; chunk ch at ch^row
#pragma unroll
      for (int i = 0; i < 16; i++) {
        int e   = i * 256 + t;        // 16B chunk id 0..4095
        int row = e >> 6;
        int ch  = e & 63;
        *(uint4*)(s_h + row * 512 + (ch ^ row) * 8) =
            *(const uint4*)(ring + ((size_t)row * NS + ttp) * 1024 + dir * NH + ch * 8);
      }
      __syncthreads();
      const int r = w * 16 + l16;
#pragma unroll
      for (int kt = 0; kt < 16; kt++) {
        int chunk = (kt * 4 + quad) ^ r;
        half8_t af = *(const half8_t*)(s_h + r * 512 + chunk * 8);
#pragma unroll
        for (int nt = 0; nt < 4; nt++)
          acc[nt] = __builtin_amdgcn_mfma_f32_16x16x32_f16(af, ufrag[kt][nt], acc[nt], 0, 0, 0);
      }
    }

    // dump z = acc + xz(prefetched) into s_z[64][68]; gate g == n-tile nt
#pragma unroll
    for (int nt = 0; nt < 4; nt++)
#pragma unroll
      for (int r4 = 0; r4 < 4; r4++)
        s_z[(row0 + r4) * 68 + nt * 16 + l16] = acc[nt][r4] + __half2float(xzr[nt * 4 + r4]);
    __syncthreads();

    // gate update: 4 states per thread (row srow, cols jb..jb+3)
    {
      bool m = text[srow * NS + tt] != 0;
      float4 zi = *(const float4*)&s_z[srow * 68 + 0  + jb];
      float4 zf = *(const float4*)&s_z[srow * 68 + 16 + jb];
      float4 zg = *(const float4*)&s_z[srow * 68 + 32 + jb];
      float4 zo = *(const float4*)&s_z[srow * 68 + 48 + jb];
      float ziv[4] = {zi.x, zi.y, zi.z, zi.w};
      float zfv[4] = {zf.x, zf.y, zf.z, zf.w};
      float zgv[4] = {zg.x, zg.y, zg.z, zg.w};
      float zov[4] = {zo.x, zo.y, zo.z, zo.w};
      union { __half h[4]; unsigned long long u; } pk;
#pragma unroll
      for (int u = 0; u < 4; u++) {
        float ig = 1.f / (1.f + expf(-ziv[u]));
        float fg = 1.f / (1.f + expf(-zfv[u]));
        float gv = tanhf(zgv[u]);
        float og = 1.f / (1.f + expf(-zov[u]));
        float cn = fg * c_st[u] + ig * gv;
        float hn = og * tanhf(cn);
        if (m) { c_st[u] = cn; h_st[u] = hn; }
        pk.h[u] = __float2half(h_st[u]);
      }
      // write-through (LLC) 8B store into ring slot tt
      size_t haddr = ((size_t)srow * NS + tt) * 1024 + dir * NH + hc0 + jb;
      __hip_atomic_store((unsigned long long*)ring + (haddr >> 2), pk.u,
                         __ATOMIC_RELAXED, __HIP_MEMORY_SCOPE_AGENT);
      if (hT_out && s == NS - 1) {
#pragma unroll
        for (int u = 0; u < 4; u++)
          hT_out[(size_t)srow * 1024 + dir * NH + hc0 + jb + u] = h_st[u];
      }
    }

    if (s < NS - 1) {
      // prefetch xz(s+1) BEFORE the drain: latency hides under store-ack + poll
      {
        int ttn = dir ? (tt - 1) : (tt + 1);
#pragma unroll
        for (int nt = 0; nt < 4; nt++)
#pragma unroll
          for (int r4 = 0; r4 < 4; r4++)
            xzr[nt * 4 + r4] = xz[((size_t)(row0 + r4) * NS + ttn) * N4H + nt * NH + hc0 + l16];
      }
      __syncthreads();      // drains vmcnt(0): ring stores LLC-visible; s_z reads done
      if (t < 64) {
        if (t == 0)
          __hip_atomic_store(myflags + cblk, s + 1, __ATOMIC_RELAXED, __HIP_MEMORY_SCOPE_AGENT);
        int it = 0;
        while (true) {
          int f = __hip_atomic_load(myflags + (lane & 31),
                                    __ATOMIC_RELAXED, __HIP_MEMORY_SCOPE_AGENT);
          if (__all(f >= s + 1)) break;
          __builtin_amdgcn_s_sleep(2);
          if (((++it) & 1023) == 0) {
            if (it > 200000)
              __hip_atomic_store(abortf, 1, __ATOMIC_RELAXED, __HIP_MEMORY_SCOPE_AGENT);
            if (__hip_atomic_load(abortf, __ATOMIC_RELAXED, __HIP_MEMORY_SCOPE_AGENT)) break;
          }
        }
        if (t == 0)
          s_brk = __hip_atomic_load(abortf, __ATOMIC_RELAXED, __HIP_MEMORY_SCOPE_AGENT);
      }
      __syncthreads();      // barrier passed; also protects s_h rewrite next iter
      if (s_brk) return;    // fast-fail instead of hang
    }
  }
}

// ---------- fp32 SMEM GEMM (head only) ----------
template <int ACT>
__global__ __launch_bounds__(256) void gemm_kernel(
    const float* __restrict__ A, const float* __restrict__ W,
    const float* __restrict__ bias, float* __restrict__ C,
    int M, int N, int K) {
  __shared__ __align__(16) float As[8][128];
  __shared__ __align__(16) float Bs[8][128];
  const int t  = threadIdx.x;
  const int bn = blockIdx.x * 128;
  const int bm = blockIdx.y * 128;
  const int tx = t & 15, ty = t >> 4;
  const int lm  = t >> 1;
  const int lk4 = (t & 1) * 4;
  const int lbk = t >> 5;
  const int lbn = (t & 31) * 4;
  float acc[8][8];
#pragma unroll
  for (int i = 0; i < 8; i++)
#pragma unroll
    for (int j = 0; j < 8; j++) acc[i][j] = 0.f;

  for (int k0 = 0; k0 < K; k0 += 8) {
#pragma unroll
    for (int i = 0; i < 4; i++) {
      int k = k0 + lk4 + i;
      int m = bm + lm;
      float v = 0.f;
      if (k < K && m < M) v = A[(size_t)m * K + k];
      As[lk4 + i][lm] = v;
    }
    {
      int k = k0 + lbk;
      float4 v = make_float4(0.f, 0.f, 0.f, 0.f);
      if (k < K) v = *(const float4*)(W + (size_t)k * N + bn + lbn);
      *(float4*)(&Bs[lbk][lbn]) = v;
    }
    __syncthreads();
#pragma unroll
    for (int kk = 0; kk < 8; kk++) {
      float a[8], b[8];
      *(float4*)(a)     = *(const float4*)(&As[kk][ty * 8]);
      *(float4*)(a + 4) = *(const float4*)(&As[kk][ty * 8 + 4]);
      *(float4*)(b)     = *(const float4*)(&Bs[kk][tx * 8]);
      *(float4*)(b + 4) = *(const float4*)(&Bs[kk][tx * 8 + 4]);
#pragma unroll
      for (int i = 0; i < 8; i++)
#pragma unroll
        for (int j = 0; j < 8; j++) acc[i][j] += a[i] * b[j];
    }
    __syncthreads();
  }
  float4 bv0 = *(const float4*)(bias + bn + tx * 8);
  float4 bv1 = *(const float4*)(bias + bn + tx * 8 + 4);
#pragma unroll
  for (int i = 0; i < 8; i++) {
    int m = bm + ty * 8 + i;
    if (m >= M) continue;
    float4 o0, o1;
    o0.x = acc[i][0] + bv0.x; o0.y = acc[i][1] + bv0.y;
    o0.z = acc[i][2] + bv0.z; o0.w = acc[i][3] + bv0.w;
    o1.x = acc[i][4] + bv1.x; o1.y = acc[i][5] + bv1.y;
    o1.z = acc[i][6] + bv1.z; o1.w = acc[i][7] + bv1.w;
    if (ACT == 1) {
      o0.x = o0.x >= 0.f ? o0.x : 0.2f * o0.x;  o0.y = o0.y >= 0.f ? o0.y : 0.2f * o0.y;
      o0.z = o0.z >= 0.f ? o0.z : 0.2f * o0.z;  o0.w = o0.w >= 0.f ? o0.w : 0.2f * o0.w;
      o1.x = o1.x >= 0.f ? o1.x : 0.2f * o1.x;  o1.y = o1.y >= 0.f ? o1.y : 0.2f * o1.y;
      o1.z = o1.z >= 0.f ? o1.z : 0.2f * o1.z;  o1.w = o1.w >= 0.f ? o1.w : 0.2f * o1.w;
    }
    *(float4*)(C + (size_t)m * N + bn + tx * 8)     = o0;
    *(float4*)(C + (size_t)m * N + bn + tx * 8 + 4) = o1;
  }
}

__global__ void final_kernel(const float* __restrict__ a1, const float* __restrict__ w,
                             const float* __restrict__ bias, float* __restrict__ out) {
  const int b = blockIdx.x, t = threadIdx.x;
  float v = a1[b * 256 + t] * w[t];
#pragma unroll
  for (int off = 32; off > 0; off >>= 1) v += __shfl_down(v, off, 64);
  __shared__ float red[4];
  if ((t & 63) == 0) red[t >> 6] = v;
  __syncthreads();
  if (t == 0) out[b] = (red[0] + red[1]) + (red[2] + red[3]) + bias[0];
}

extern "C" void kernel_launch(void* const* d_in, const int* in_sizes, int n_in,
                              void* d_out, int out_size, void* d_ws, size_t ws_size,
                              hipStream_t stream) {
  const int*   text = (const int*)  d_in[0];
  const float* emb  = (const float*)d_in[1];
  const float* W0f  = (const float*)d_in[2];
  const float* U0f  = (const float*)d_in[3];
  const float* b0f  = (const float*)d_in[4];
  const float* W0b  = (const float*)d_in[5];
  const float* U0b  = (const float*)d_in[6];
  const float* b0b  = (const float*)d_in[7];
  const float* W1f  = (const float*)d_in[8];
  const float* U1f  = (const float*)d_in[9];
  const float* b1f  = (const float*)d_in[10];
  const float* W1b  = (const float*)d_in[11];
  const float* U1b  = (const float*)d_in[12];
  const float* b1b  = (const float*)d_in[13];
  const float* d0w  = (const float*)d_in[14];
  const float* d0b  = (const float*)d_in[15];
  const float* d1w  = (const float*)d_in[16];
  const float* d1b  = (const float*)d_in[17];
  const float* d2w  = (const float*)d_in[18];
  const float* d2b  = (const float*)d_in[19];
  float* out = (float*)d_out;

  // workspace carve: identical to proven footprint (168,955,904 B)
  char* p = (char*)d_ws;
  __half* xzA = (__half*)p;  p += (size_t)NB * NS * N4H * 2;
  __half* xzB = (__half*)p;  p += (size_t)NB * NS * N4H * 2;
  char* region1 = p;         p += (size_t)NB * NS * 1024 * 2;
  _Float16* x_emb = (_Float16*)region1;   // dead before hs0 written
  __half*   hs0   = (__half*)region1;     // layer-0 ring == hs output; layer-1 ring reuses
  __half* hp0  = (__half*)p;  p += 64 * 1024 * 2;   // unused (carve kept identical)
  __half* hp1  = (__half*)p;  p += 64 * 1024 * 2;   // unused
  int*    cnt  = (int*)p;     p += 64 * 1024 * 4;   // barrier flags + abort
  float*  feat = (float*)p;   p += 64 * 1024 * 4;
  float*  a0   = (float*)p;   p += 64 * 512 * 4;
  float*  a1   = (float*)p;   p += 64 * 256 * 4;
  (void)hp0; (void)hp1;
  int* flags0 = cnt;          // layer0: [dir*32 + cblk], monotonic step count
  int* flags1 = cnt + 64;     // layer1
  int* abortf = cnt + 128;

  hipMemsetAsync(cnt, 0, 129 * sizeof(int), stream);
  hipLaunchKernelGGL(embed_f16_kernel, dim3(4096), dim3(256), 0, stream, text, emb, x_emb);

  dim3 gmf(16, 128);
  hipLaunchKernelGGL(gemm_mfma_kernel, gmf, dim3(256), 0, stream, x_emb, W0f, b0f, xzA, 16384, N4H, NDP, ND);
  hipLaunchKernelGGL(gemm_mfma_kernel, gmf, dim3(256), 0, stream, x_emb, W0b, b0b, xzB, 16384, N4H, NDP, ND);

  hipLaunchKernelGGL(scan_ring_kernel, dim3(256), dim3(256), 0, stream,
                     xzA, xzB, U0f, U0b, text, hs0, flags0, abortf, (float*)nullptr);

  hipLaunchKernelGGL(gemm_mfma_kernel, gmf, dim3(256), 0, stream, (const _Float16*)hs0, W1f, b1f, xzA, 16384, N4H, 1024, 1024);
  hipLaunchKernelGGL(gemm_mfma_kernel, gmf, dim3(256), 0, stream, (const _Float16*)hs0, W1b, b1b, xzB, 16384, N4H, 1024, 1024);

  // layer-1 ring reuses region1 (hs0 dead after the two GEMMs above)
  hipLaunchKernelGGL(scan_ring_kernel, dim3(256), dim3(256), 0, stream,
                     xzA, xzB, U1f, U1b, text, hs0, flags1, abortf, feat);

  gemm_kernel<1><<<dim3(4, 1), dim3(256), 0, stream>>>(feat, d0w, d0b, a0, 64, 512, 1024);
  gemm_kernel<1><<<dim3(2, 1), dim3(256), 0, stream>>>(a0, d1w, d1b, a1, 64, 256, 512);
  hipLaunchKernelGGL(final_kernel, dim3(64), dim3(256), 0, stream, a1, d2w, d2b, out);
}

// Round 4
// 4043.668 us; speedup vs baseline: 1.4107x; 1.4107x over previous
//
// R15: un-serialize the scan step. R14 proved placement (FETCH 402->86MB) but
// dur didn't move -> scan is issue-serialization bound, not locality bound:
// (1) ufrag eats ~250 regs so the 16-iter global->reg->LDS staging loop can
//     keep only ~2-4 loads in flight = ~16/3 serialized LLC RTTs per step.
//     Fix: global_load_lds width=16 DMA (no VGPR round-trip, all in flight),
//     XOR swizzle moved to the GLOBAL source side (rule #21): LDS linear,
//     src chunk (row=q>>6, ch=(q&63)^row) -- data placement bit-identical.
// (2) step-end __syncthreads drains vmcnt(0) AFTER the 16 xz HBM prefetch
//     loads -> ~1us on the flag-signal path every step. Fix: prefetch AFTER
//     the flag-poll release barrier; it overlaps next step's staging DMA and
//     both drain together at the staging barrier.
// Protocol (AGENT ring/flag stores, poll, __syncthreads barriers) and
// placement (grid 256, b&7<2) identical to proven R14.
#include <hip/hip_runtime.h>
#include <hip/hip_fp16.h>
#include <math.h>

#define NB   64
#define NS   256
#define ND   300
#define NDP  320
#define NH   512
#define N4H  2048

typedef _Float16 half8_t __attribute__((ext_vector_type(8)));
typedef float    f32x4_t __attribute__((ext_vector_type(4)));

typedef const __attribute__((address_space(1))) unsigned int gas_u32;
typedef __attribute__((address_space(3))) unsigned int las_u32;

// ---------- embedding: gather + fp16 convert + zero-pad K to 320 ----------
__global__ void embed_f16_kernel(const int* __restrict__ text,
                                 const float* __restrict__ emb,
                                 _Float16* __restrict__ x) {
  int idx = blockIdx.x * 256 + threadIdx.x;
  const int total = NB * NS * NDP;
  for (; idx < total; idx += gridDim.x * 256) {
    int bs = idx / NDP;
    int d  = idx - bs * NDP;
    x[idx] = (d < ND) ? (_Float16)emb[(size_t)text[bs] * ND + d] : (_Float16)0.f;
  }
}

// ---------- MFMA GEMM with in-LDS weight transpose (unchanged from R6) ----------
__global__ __launch_bounds__(256) void gemm_mfma_kernel(
    const _Float16* __restrict__ A, const float* __restrict__ W,
    const float* __restrict__ bias, __half* __restrict__ C,
    int M, int N, int K, int Kw) {
  __shared__ __align__(16) _Float16 as[128][40];
  __shared__ __align__(16) _Float16 ws16[128][40];
  __shared__ __align__(16) float    ws32[32][132];
  const int t = threadIdx.x;
  const int w = t >> 6;
  const int l = t & 63;
  const int lane16 = l & 15;
  const int kq = l >> 4;
  const int bm = blockIdx.y * 128;
  const int bn = blockIdx.x * 128;
  const int lr  = t >> 2;
  const int lsg = t & 3;
  const int wk  = t >> 3;
  const int wns = t & 7;
  const int rn  = t >> 1;
  const int rk0 = (t & 1) * 2;

  f32x4_t acc[2][8];
#pragma unroll
  for (int i = 0; i < 2; i++)
#pragma unroll
    for (int j = 0; j < 8; j++) acc[i][j] = (f32x4_t){0.f, 0.f, 0.f, 0.f};

  for (int k0 = 0; k0 < K; k0 += 32) {
#pragma unroll
    for (int h = 0; h < 2; h++) {
      int m = h * 64 + lr;
      *(uint4*)&as[m][lsg * 8] = *(const uint4*)(A + (size_t)(bm + m) * K + k0 + lsg * 8);
    }
    if (k0 + wk < Kw) {
#pragma unroll
      for (int i = 0; i < 4; i++)
        *(float4*)&ws32[wk][wns * 16 + i * 4] =
            *(const float4*)(W + (size_t)(k0 + wk) * N + bn + wns * 16 + i * 4);
    } else {
#pragma unroll
      for (int i = 0; i < 4; i++)
        *(float4*)&ws32[wk][wns * 16 + i * 4] = make_float4(0.f, 0.f, 0.f, 0.f);
    }
    __syncthreads();
#pragma unroll
    for (int g = 0; g < 2; g++) {
      int kqq = rk0 + g;
      half8_t hv;
#pragma unroll
      for (int jj = 0; jj < 8; jj++) hv[jj] = (_Float16)ws32[kqq * 8 + jj][rn];
      *(half8_t*)&ws16[rn][kqq * 8] = hv;
    }
    __syncthreads();
    half8_t afrag[2];
#pragma unroll
    for (int i = 0; i < 2; i++)
      afrag[i] = *(const half8_t*)&as[w * 32 + i * 16 + lane16][kq * 8];
#pragma unroll
    for (int j = 0; j < 8; j++) {
      half8_t bfrag = *(const half8_t*)&ws16[j * 16 + lane16][kq * 8];
#pragma unroll
      for (int i = 0; i < 2; i++)
        acc[i][j] = __builtin_amdgcn_mfma_f32_16x16x32_f16(afrag[i], bfrag, acc[i][j], 0, 0, 0);
    }
    __syncthreads();
  }
#pragma unroll
  for (int j = 0; j < 8; j++) {
    int col = bn + j * 16 + lane16;
    float bv = bias[col];
#pragma unroll
    for (int i = 0; i < 2; i++) {
      int rbase = bm + w * 32 + i * 16 + kq * 4;
#pragma unroll
      for (int r = 0; r < 4; r++)
        C[(size_t)(rbase + r) * N + col] = __float2half(acc[i][j][r] + bv);
    }
  }
}

// ---------- persistent bi-LSTM scan ----------
// Grid 256 x 256thr. Block b participates iff (b&7)<2: dir=b&7, cblk=b>>3.
// h(s-1) staging: 16x global_load_lds(16B) DMA per thread, LDS linear,
// XOR swizzle applied to the GLOBAL source chunk -> same LDS image as R14.
// xz prefetch issued after the flag release barrier (overlaps next staging).
#define PREFETCH_XZ()                                                         \
  {                                                                           \
    _Pragma("unroll")                                                         \
    for (int nt = 0; nt < 4; nt++)                                            \
      _Pragma("unroll")                                                       \
      for (int r4 = 0; r4 < 4; r4++)                                          \
        xzr[nt * 4 + r4] =                                                    \
            xz[((size_t)(row0 + r4) * NS + ttn) * N4H + nt * NH + hc0 + l16]; \
  }

__global__ __launch_bounds__(256, 1) void scan_ring_kernel(
    const __half* __restrict__ xzf, const __half* __restrict__ xzb,
    const float* __restrict__ Uf, const float* __restrict__ Ub,
    const int* __restrict__ text,
    __half* ring,
    int* flags, int* abortf,
    float* __restrict__ hT_out) {
  __shared__ __align__(16) _Float16 s_h[64 * 512];   // 64KB h tile (chunk q at q*16B)
  __shared__ __align__(16) float    s_z[64 * 68];    // 17.4KB z
  __shared__ int s_brk;

  const int t  = threadIdx.x;
  const int b  = blockIdx.x;
  const int grp = b & 7;
  if (grp >= 2) return;                // blocks on XCD2..7: exit immediately
  const int dir  = grp;
  const int cblk = b >> 3;             // 0..31
  const int hc0  = cblk * 16;
  const __half* xz = dir ? xzb : xzf;
  const float* U = dir ? Ub : Uf;
  int* myflags = flags + dir * 32;

  const int w    = t >> 6;          // wave = m-tile (rows w*16..w*16+16)
  const int lane = t & 63;
  const int l16  = lane & 15;
  const int quad = lane >> 4;

  // precomputed per-thread staging geometry: chunk q = i*256 + t
  // row(q)=q>>6, src ch = (q&63)^row  (inverse swizzle on the source side)
  int st_row[16], st_ch[16];
#pragma unroll
  for (int i = 0; i < 16; i++) {
    int q = i * 256 + t;
    st_row[i] = q >> 6;
    st_ch[i]  = (q & 63) ^ (q >> 6);
  }

  // persistent U B-frags: ufrag[kt][nt][jj] = U[kt*32+quad*8+jj][nt*512+hc0+l16]
  half8_t ufrag[16][4];
#pragma unroll
  for (int nt = 0; nt < 4; nt++) {
    int col = nt * NH + hc0 + l16;
#pragma unroll
    for (int kt = 0; kt < 16; kt++)
#pragma unroll
      for (int jj = 0; jj < 8; jj++)
        ufrag[kt][nt][jj] = (_Float16)U[(size_t)(kt * 32 + quad * 8 + jj) * N4H + col];
  }

  // LSTM state: thread owns row = t>>2, cols jb..jb+3 (jb = (t&3)*4)
  const int srow = t >> 2;
  const int jb   = (t & 3) * 4;
  const int row0 = w * 16 + quad * 4;
  float c_st[4] = {0.f, 0.f, 0.f, 0.f}, h_st[4] = {0.f, 0.f, 0.f, 0.f};

  // xz prefetch registers (16 scalars per thread, step-s values)
  __half xzr[16];
  {
    int ttn = dir ? (NS - 1) : 0;
    PREFETCH_XZ();
  }

  for (int s = 0; s < NS; s++) {
    const int tt = dir ? (NS - 1 - s) : s;
    f32x4_t acc[4] = {{0.f,0.f,0.f,0.f},{0.f,0.f,0.f,0.f},{0.f,0.f,0.f,0.f},{0.f,0.f,0.f,0.f}};

    if (s > 0) {
      const int ttp = dir ? (tt + 1) : (tt - 1);   // slot holding h(s-1)
      // stage h(s-1): 16x 16B DMA per thread, no VGPR round-trip, all in
      // flight. LDS dest linear (wave-uniform base + lane*16); src chunk
      // carries the XOR swizzle -> LDS image identical to R14's.
#pragma unroll
      for (int i = 0; i < 16; i++) {
        const __half* gp = ring + ((size_t)st_row[i] * NS + ttp) * 1024
                                + dir * NH + st_ch[i] * 8;
        __builtin_amdgcn_global_load_lds((gas_u32*)gp,
                                         (las_u32*)(s_h + (size_t)(i * 256 + t) * 8),
                                         16, 0, 0);
      }
      __syncthreads();   // drains DMA (vmcnt) + last step's xz prefetch together
      const int r = w * 16 + l16;
#pragma unroll
      for (int kt = 0; kt < 16; kt++) {
        int chunk = (kt * 4 + quad) ^ r;
        half8_t af = *(const half8_t*)(s_h + r * 512 + chunk * 8);
#pragma unroll
        for (int nt = 0; nt < 4; nt++)
          acc[nt] = __builtin_amdgcn_mfma_f32_16x16x32_f16(af, ufrag[kt][nt], acc[nt], 0, 0, 0);
      }
    }

    // dump z = acc + xz(prefetched) into s_z[64][68]; gate g == n-tile nt
#pragma unroll
    for (int nt = 0; nt < 4; nt++)
#pragma unroll
      for (int r4 = 0; r4 < 4; r4++)
        s_z[(row0 + r4) * 68 + nt * 16 + l16] = acc[nt][r4] + __half2float(xzr[nt * 4 + r4]);
    __syncthreads();

    // gate update: 4 states per thread (row srow, cols jb..jb+3)
    {
      bool m = text[srow * NS + tt] != 0;
      float4 zi = *(const float4*)&s_z[srow * 68 + 0  + jb];
      float4 zf = *(const float4*)&s_z[srow * 68 + 16 + jb];
      float4 zg = *(const float4*)&s_z[srow * 68 + 32 + jb];
      float4 zo = *(const float4*)&s_z[srow * 68 + 48 + jb];
      float ziv[4] = {zi.x, zi.y, zi.z, zi.w};
      float zfv[4] = {zf.x, zf.y, zf.z, zf.w};
      float zgv[4] = {zg.x, zg.y, zg.z, zg.w};
      float zov[4] = {zo.x, zo.y, zo.z, zo.w};
      union { __half h[4]; unsigned long long u; } pk;
#pragma unroll
      for (int u = 0; u < 4; u++) {
        float ig = 1.f / (1.f + expf(-ziv[u]));
        float fg = 1.f / (1.f + expf(-zfv[u]));
        float gv = tanhf(zgv[u]);
        float og = 1.f / (1.f + expf(-zov[u]));
        float cn = fg * c_st[u] + ig * gv;
        float hn = og * tanhf(cn);
        if (m) { c_st[u] = cn; h_st[u] = hn; }
        pk.h[u] = __float2half(h_st[u]);
      }
      // write-through (LLC) 8B store into ring slot tt
      size_t haddr = ((size_t)srow * NS + tt) * 1024 + dir * NH + hc0 + jb;
      __hip_atomic_store((unsigned long long*)ring + (haddr >> 2), pk.u,
                         __ATOMIC_RELAXED, __HIP_MEMORY_SCOPE_AGENT);
      if (hT_out && s == NS - 1) {
#pragma unroll
        for (int u = 0; u < 4; u++)
          hT_out[(size_t)srow * 1024 + dir * NH + hc0 + jb + u] = h_st[u];
      }
    }

    if (s < NS - 1) {
      __syncthreads();      // drains vmcnt(0): ring stores LLC-visible; s_z reads done
                            // (xz prefetch NOT outstanding here -> cheap drain)
      if (t < 64) {
        if (t == 0)
          __hip_atomic_store(myflags + cblk, s + 1, __ATOMIC_RELAXED, __HIP_MEMORY_SCOPE_AGENT);
        int it = 0;
        while (true) {
          int f = __hip_atomic_load(myflags + (lane & 31),
                                    __ATOMIC_RELAXED, __HIP_MEMORY_SCOPE_AGENT);
          if (__all(f >= s + 1)) break;
          __builtin_amdgcn_s_sleep(2);
          if (((++it) & 1023) == 0) {
            if (it > 200000)
              __hip_atomic_store(abortf, 1, __ATOMIC_RELAXED, __HIP_MEMORY_SCOPE_AGENT);
            if (__hip_atomic_load(abortf, __ATOMIC_RELAXED, __HIP_MEMORY_SCOPE_AGENT)) break;
          }
        }
        if (t == 0)
          s_brk = __hip_atomic_load(abortf, __ATOMIC_RELAXED, __HIP_MEMORY_SCOPE_AGENT);
      }
      __syncthreads();      // release; also protects s_h rewrite next iter
      if (s_brk) return;    // fast-fail instead of hang
      // prefetch xz(s+1) AFTER the barrier: off the signal path; latency
      // overlaps next step's staging DMA (drained together there)
      {
        const int ttn = dir ? (tt - 1) : (tt + 1);
        PREFETCH_XZ();
      }
    }
  }
}

// ---------- fp32 SMEM GEMM (head only) ----------
template <int ACT>
__global__ __launch_bounds__(256) void gemm_kernel(
    const float* __restrict__ A, const float* __restrict__ W,
    const float* __restrict__ bias, float* __restrict__ C,
    int M, int N, int K) {
  __shared__ __align__(16) float As[8][128];
  __shared__ __align__(16) float Bs[8][128];
  const int t  = threadIdx.x;
  const int bn = blockIdx.x * 128;
  const int bm = blockIdx.y * 128;
  const int tx = t & 15, ty = t >> 4;
  const int lm  = t >> 1;
  const int lk4 = (t & 1) * 4;
  const int lbk = t >> 5;
  const int lbn = (t & 31) * 4;
  float acc[8][8];
#pragma unroll
  for (int i = 0; i < 8; i++)
#pragma unroll
    for (int j = 0; j < 8; j++) acc[i][j] = 0.f;

  for (int k0 = 0; k0 < K; k0 += 8) {
#pragma unroll
    for (int i = 0; i < 4; i++) {
      int k = k0 + lk4 + i;
      int m = bm + lm;
      float v = 0.f;
      if (k < K && m < M) v = A[(size_t)m * K + k];
      As[lk4 + i][lm] = v;
    }
    {
      int k = k0 + lbk;
      float4 v = make_float4(0.f, 0.f, 0.f, 0.f);
      if (k < K) v = *(const float4*)(W + (size_t)k * N + bn + lbn);
      *(float4*)(&Bs[lbk][lbn]) = v;
    }
    __syncthreads();
#pragma unroll
    for (int kk = 0; kk < 8; kk++) {
      float a[8], b[8];
      *(float4*)(a)     = *(const float4*)(&As[kk][ty * 8]);
      *(float4*)(a + 4) = *(const float4*)(&As[kk][ty * 8 + 4]);
      *(float4*)(b)     = *(const float4*)(&Bs[kk][tx * 8]);
      *(float4*)(b + 4) = *(const float4*)(&Bs[kk][tx * 8 + 4]);
#pragma unroll
      for (int i = 0; i < 8; i++)
#pragma unroll
        for (int j = 0; j < 8; j++) acc[i][j] += a[i] * b[j];
    }
    __syncthreads();
  }
  float4 bv0 = *(const float4*)(bias + bn + tx * 8);
  float4 bv1 = *(const float4*)(bias + bn + tx * 8 + 4);
#pragma unroll
  for (int i = 0; i < 8; i++) {
    int m = bm + ty * 8 + i;
    if (m >= M) continue;
    float4 o0, o1;
    o0.x = acc[i][0] + bv0.x; o0.y = acc[i][1] + bv0.y;
    o0.z = acc[i][2] + bv0.z; o0.w = acc[i][3] + bv0.w;
    o1.x = acc[i][4] + bv1.x; o1.y = acc[i][5] + bv1.y;
    o1.z = acc[i][6] + bv1.z; o1.w = acc[i][7] + bv1.w;
    if (ACT == 1) {
      o0.x = o0.x >= 0.f ? o0.x : 0.2f * o0.x;  o0.y = o0.y >= 0.f ? o0.y : 0.2f * o0.y;
      o0.z = o0.z >= 0.f ? o0.z : 0.2f * o0.z;  o0.w = o0.w >= 0.f ? o0.w : 0.2f * o0.w;
      o1.x = o1.x >= 0.f ? o1.x : 0.2f * o1.x;  o1.y = o1.y >= 0.f ? o1.y : 0.2f * o1.y;
      o1.z = o1.z >= 0.f ? o1.z : 0.2f * o1.z;  o1.w = o1.w >= 0.f ? o1.w : 0.2f * o1.w;
    }
    *(float4*)(C + (size_t)m * N + bn + tx * 8)     = o0;
    *(float4*)(C + (size_t)m * N + bn + tx * 8 + 4) = o1;
  }
}

__global__ void final_kernel(const float* __restrict__ a1, const float* __restrict__ w,
                             const float* __restrict__ bias, float* __restrict__ out) {
  const int b = blockIdx.x, t = threadIdx.x;
  float v = a1[b * 256 + t] * w[t];
#pragma unroll
  for (int off = 32; off > 0; off >>= 1) v += __shfl_down(v, off, 64);
  __shared__ float red[4];
  if ((t & 63) == 0) red[t >> 6] = v;
  __syncthreads();
  if (t == 0) out[b] = (red[0] + red[1]) + (red[2] + red[3]) + bias[0];
}

extern "C" void kernel_launch(void* const* d_in, const int* in_sizes, int n_in,
                              void* d_out, int out_size, void* d_ws, size_t ws_size,
                              hipStream_t stream) {
  const int*   text = (const int*)  d_in[0];
  const float* emb  = (const float*)d_in[1];
  const float* W0f  = (const float*)d_in[2];
  const float* U0f  = (const float*)d_in[3];
  const float* b0f  = (const float*)d_in[4];
  const float* W0b  = (const float*)d_in[5];
  const float* U0b  = (const float*)d_in[6];
  const float* b0b  = (const float*)d_in[7];
  const float* W1f  = (const float*)d_in[8];
  const float* U1f  = (const float*)d_in[9];
  const float* b1f  = (const float*)d_in[10];
  const float* W1b  = (const float*)d_in[11];
  const float* U1b  = (const float*)d_in[12];
  const float* b1b  = (const float*)d_in[13];
  const float* d0w  = (const float*)d_in[14];
  const float* d0b  = (const float*)d_in[15];
  const float* d1w  = (const float*)d_in[16];
  const float* d1b  = (const float*)d_in[17];
  const float* d2w  = (const float*)d_in[18];
  const float* d2b  = (const float*)d_in[19];
  float* out = (float*)d_out;

  // workspace carve: identical to proven footprint (168,955,904 B)
  char* p = (char*)d_ws;
  __half* xzA = (__half*)p;  p += (size_t)NB * NS * N4H * 2;
  __half* xzB = (__half*)p;  p += (size_t)NB * NS * N4H * 2;
  char* region1 = p;         p += (size_t)NB * NS * 1024 * 2;
  _Float16* x_emb = (_Float16*)region1;   // dead before hs0 written
  __half*   hs0   = (__half*)region1;     // layer-0 ring == hs output; layer-1 ring reuses
  __half* hp0  = (__half*)p;  p += 64 * 1024 * 2;   // unused (carve kept identical)
  __half* hp1  = (__half*)p;  p += 64 * 1024 * 2;   // unused
  int*    cnt  = (int*)p;     p += 64 * 1024 * 4;   // barrier flags + abort
  float*  feat = (float*)p;   p += 64 * 1024 * 4;
  float*  a0   = (float*)p;   p += 64 * 512 * 4;
  float*  a1   = (float*)p;   p += 64 * 256 * 4;
  (void)hp0; (void)hp1;
  int* flags0 = cnt;          // layer0: [dir*32 + cblk], monotonic step count
  int* flags1 = cnt + 64;     // layer1
  int* abortf = cnt + 128;

  hipMemsetAsync(cnt, 0, 129 * sizeof(int), stream);
  hipLaunchKernelGGL(embed_f16_kernel, dim3(4096), dim3(256), 0, stream, text, emb, x_emb);

  dim3 gmf(16, 128);
  hipLaunchKernelGGL(gemm_mfma_kernel, gmf, dim3(256), 0, stream, x_emb, W0f, b0f, xzA, 16384, N4H, NDP, ND);
  hipLaunchKernelGGL(gemm_mfma_kernel, gmf, dim3(256), 0, stream, x_emb, W0b, b0b, xzB, 16384, N4H, NDP, ND);

  hipLaunchKernelGGL(scan_ring_kernel, dim3(256), dim3(256), 0, stream,
                     xzA, xzB, U0f, U0b, text, hs0, flags0, abortf, (float*)nullptr);

  hipLaunchKernelGGL(gemm_mfma_kernel, gmf, dim3(256), 0, stream, (const _Float16*)hs0, W1f, b1f, xzA, 16384, N4H, 1024, 1024);
  hipLaunchKernelGGL(gemm_mfma_kernel, gmf, dim3(256), 0, stream, (const _Float16*)hs0, W1b, b1b, xzB, 16384, N4H, 1024, 1024);

  // layer-1 ring reuses region1 (hs0 dead after the two GEMMs above)
  hipLaunchKernelGGL(scan_ring_kernel, dim3(256), dim3(256), 0, stream,
                     xzA, xzB, U1f, U1b, text, hs0, flags1, abortf, feat);

  gemm_kernel<1><<<dim3(4, 1), dim3(256), 0, stream>>>(feat, d0w, d0b, a0, 64, 512, 1024);
  gemm_kernel<1><<<dim3(2, 1), dim3(256), 0, stream>>>(a0, d1w, d1b, a1, 64, 256, 512);
  hipLaunchKernelGGL(final_kernel, dim3(64), dim3(256), 0, stream, a1, d2w, d2b, out);
}

// Round 6
// 3860.811 us; speedup vs baseline: 1.4775x; 1.0474x over previous
//
// R17: in-register gates + local-L2 ring stores, on R15's proven protocol.
// Re-diagnosis of R12/R13/R16 (bit-identical absmax 2.0508e-2 = max|ref| =>
// out==0 => abort path): the common element was the hand-rolled sc0 poll,
// which does NOT bypass L1 -> stale flag forever -> timeout -> abort. The
// store-scope theories were phantoms. Proven-robust poll = __hip_atomic_load
// AGENT (compiler emits correct L1-bypass bits). This round keeps that and:
//  A. gates computed directly in MFMA register layout (thread owns rows
//     row0..+3 x col hc0+l16 for all 4 gates) -- s_z dump/barrier/re-read was
//     a redundant transpose. Removes 1 barrier + LDS traffic + bank conflicts.
//  B. __expf + branch-free tanh (err << 4.1e-4 threshold).
//  C. all-wave AGENT poll; release barrier dropped (no LDS hazard: last s_h
//     read is >=2 barriers before staging rewrite; abort = uniform return).
//  D. ring h-stores plain 2B (CDNA L1 is write-through -> ack at shared
//     home-XCD L2 ~250cyc vs ~900 LLC; staging DMA reads same L2; cross-
//     dispatch readers covered by dispatch-end writeback -- proven by feat).
// Flag store stays AGENT (proven). Placement/staging/carve identical to R15.
#include <hip/hip_runtime.h>
#include <hip/hip_fp16.h>
#include <math.h>

#define NB   64
#define NS   256
#define ND   300
#define NDP  320
#define NH   512
#define N4H  2048

typedef _Float16 half8_t __attribute__((ext_vector_type(8)));
typedef float    f32x4_t __attribute__((ext_vector_type(4)));

typedef const __attribute__((address_space(1))) unsigned int gas_u32;
typedef __attribute__((address_space(3))) unsigned int las_u32;

__device__ __forceinline__ float fast_sig(float x) {
  return 1.f / (1.f + __expf(-x));
}
__device__ __forceinline__ float fast_tanh(float x) {
  float ax = fabsf(x);
  float e  = __expf(2.f * ax);          // inf for large ax -> r -> 1
  float r  = 1.f - 2.f / (e + 1.f);
  return copysignf(r, x);
}

// ---------- embedding: gather + fp16 convert + zero-pad K to 320 ----------
__global__ void embed_f16_kernel(const int* __restrict__ text,
                                 const float* __restrict__ emb,
                                 _Float16* __restrict__ x) {
  int idx = blockIdx.x * 256 + threadIdx.x;
  const int total = NB * NS * NDP;
  for (; idx < total; idx += gridDim.x * 256) {
    int bs = idx / NDP;
    int d  = idx - bs * NDP;
    x[idx] = (d < ND) ? (_Float16)emb[(size_t)text[bs] * ND + d] : (_Float16)0.f;
  }
}

// ---------- MFMA GEMM with in-LDS weight transpose (unchanged from R6) ----------
__global__ __launch_bounds__(256) void gemm_mfma_kernel(
    const _Float16* __restrict__ A, const float* __restrict__ W,
    const float* __restrict__ bias, __half* __restrict__ C,
    int M, int N, int K, int Kw) {
  __shared__ __align__(16) _Float16 as[128][40];
  __shared__ __align__(16) _Float16 ws16[128][40];
  __shared__ __align__(16) float    ws32[32][132];
  const int t = threadIdx.x;
  const int w = t >> 6;
  const int l = t & 63;
  const int lane16 = l & 15;
  const int kq = l >> 4;
  const int bm = blockIdx.y * 128;
  const int bn = blockIdx.x * 128;
  const int lr  = t >> 2;
  const int lsg = t & 3;
  const int wk  = t >> 3;
  const int wns = t & 7;
  const int rn  = t >> 1;
  const int rk0 = (t & 1) * 2;

  f32x4_t acc[2][8];
#pragma unroll
  for (int i = 0; i < 2; i++)
#pragma unroll
    for (int j = 0; j < 8; j++) acc[i][j] = (f32x4_t){0.f, 0.f, 0.f, 0.f};

  for (int k0 = 0; k0 < K; k0 += 32) {
#pragma unroll
    for (int h = 0; h < 2; h++) {
      int m = h * 64 + lr;
      *(uint4*)&as[m][lsg * 8] = *(const uint4*)(A + (size_t)(bm + m) * K + k0 + lsg * 8);
    }
    if (k0 + wk < Kw) {
#pragma unroll
      for (int i = 0; i < 4; i++)
        *(float4*)&ws32[wk][wns * 16 + i * 4] =
            *(const float4*)(W + (size_t)(k0 + wk) * N + bn + wns * 16 + i * 4);
    } else {
#pragma unroll
      for (int i = 0; i < 4; i++)
        *(float4*)&ws32[wk][wns * 16 + i * 4] = make_float4(0.f, 0.f, 0.f, 0.f);
    }
    __syncthreads();
#pragma unroll
    for (int g = 0; g < 2; g++) {
      int kqq = rk0 + g;
      half8_t hv;
#pragma unroll
      for (int jj = 0; jj < 8; jj++) hv[jj] = (_Float16)ws32[kqq * 8 + jj][rn];
      *(half8_t*)&ws16[rn][kqq * 8] = hv;
    }
    __syncthreads();
    half8_t afrag[2];
#pragma unroll
    for (int i = 0; i < 2; i++)
      afrag[i] = *(const half8_t*)&as[w * 32 + i * 16 + lane16][kq * 8];
#pragma unroll
    for (int j = 0; j < 8; j++) {
      half8_t bfrag = *(const half8_t*)&ws16[j * 16 + lane16][kq * 8];
#pragma unroll
      for (int i = 0; i < 2; i++)
        acc[i][j] = __builtin_amdgcn_mfma_f32_16x16x32_f16(afrag[i], bfrag, acc[i][j], 0, 0, 0);
    }
    __syncthreads();
  }
#pragma unroll
  for (int j = 0; j < 8; j++) {
    int col = bn + j * 16 + lane16;
    float bv = bias[col];
#pragma unroll
    for (int i = 0; i < 2; i++) {
      int rbase = bm + w * 32 + i * 16 + kq * 4;
#pragma unroll
      for (int r = 0; r < 4; r++)
        C[(size_t)(rbase + r) * N + col] = __float2half(acc[i][j][r] + bv);
    }
  }
}

// ---------- persistent bi-LSTM scan ----------
// Grid 256 x 256thr. Block b participates iff (b&7)<2: dir=b&7, cblk=b>>3.
// Same-direction blocks co-located on one XCD (b%8 mapping, proven R14).
// h(s-1) staging: 16x global_load_lds(16B) DMA, LDS linear, XOR swizzle on
// the global source chunk. Gates fully in registers (MFMA C-layout: thread
// (w,quad,l16) owns rows row0..row0+3, h-col hc0+l16, all 4 gates as nt=0..3).
#define PREFETCH_NEXT(TTN)                                                    \
  {                                                                           \
    _Pragma("unroll")                                                         \
    for (int nt = 0; nt < 4; nt++)                                            \
      _Pragma("unroll")                                                       \
      for (int r4 = 0; r4 < 4; r4++)                                          \
        xzr[nt * 4 + r4] =                                                    \
            xz[((size_t)(row0 + r4) * NS + (TTN)) * N4H + nt * NH + hc0 + l16]; \
    _Pragma("unroll")                                                         \
    for (int r4 = 0; r4 < 4; r4++)                                            \
      tmsk[r4] = text[(row0 + r4) * NS + (TTN)];                              \
  }

__global__ __launch_bounds__(256, 1) void scan_ring_kernel(
    const __half* __restrict__ xzf, const __half* __restrict__ xzb,
    const float* __restrict__ Uf, const float* __restrict__ Ub,
    const int* __restrict__ text,
    __half* ring,
    int* flags, int* abortf,
    float* __restrict__ hT_out) {
  __shared__ __align__(16) _Float16 s_h[64 * 512];   // 64KB h tile (chunk q at q*16B)

  const int t  = threadIdx.x;
  const int b  = blockIdx.x;
  const int grp = b & 7;
  if (grp >= 2) return;                // blocks on XCD2..7: exit immediately
  const int dir  = grp;
  const int cblk = b >> 3;             // 0..31
  const int hc0  = cblk * 16;
  const __half* xz = dir ? xzb : xzf;
  const float* U = dir ? Ub : Uf;
  int* myflags = flags + dir * 32;

  const int w    = t >> 6;          // wave = m-tile (rows w*16..w*16+16)
  const int lane = t & 63;
  const int l16  = lane & 15;
  const int quad = lane >> 4;

  // precomputed per-thread staging geometry: chunk q = i*256 + t
  // row(q)=q>>6, src ch = (q&63)^row  (inverse swizzle on the source side)
  int st_row[16], st_ch[16];
#pragma unroll
  for (int i = 0; i < 16; i++) {
    int q = i * 256 + t;
    st_row[i] = q >> 6;
    st_ch[i]  = (q & 63) ^ (q >> 6);
  }

  // persistent U B-frags: ufrag[kt][nt][jj] = U[kt*32+quad*8+jj][nt*512+hc0+l16]
  half8_t ufrag[16][4];
#pragma unroll
  for (int nt = 0; nt < 4; nt++) {
    int col = nt * NH + hc0 + l16;
#pragma unroll
    for (int kt = 0; kt < 16; kt++)
#pragma unroll
      for (int jj = 0; jj < 8; jj++)
        ufrag[kt][nt][jj] = (_Float16)U[(size_t)(kt * 32 + quad * 8 + jj) * N4H + col];
  }

  // LSTM state in MFMA layout: thread owns rows row0..row0+3, col hc0+l16
  const int row0 = w * 16 + quad * 4;
  float c_st[4] = {0.f, 0.f, 0.f, 0.f}, h_st[4] = {0.f, 0.f, 0.f, 0.f};

  // prefetch registers: xz (16 scalars) + mask (4 ints), step-s values
  __half xzr[16];
  int    tmsk[4];
  {
    const int tt0 = dir ? (NS - 1) : 0;
    PREFETCH_NEXT(tt0);
  }

  for (int s = 0; s < NS; s++) {
    const int tt = dir ? (NS - 1 - s) : s;
    f32x4_t acc[4] = {{0.f,0.f,0.f,0.f},{0.f,0.f,0.f,0.f},{0.f,0.f,0.f,0.f},{0.f,0.f,0.f,0.f}};

    if (s > 0) {
      const int ttp = dir ? (tt + 1) : (tt - 1);   // slot holding h(s-1)
      // stage h(s-1): 16x 16B DMA per thread from home-XCD L2, all in flight.
#pragma unroll
      for (int i = 0; i < 16; i++) {
        const __half* gp = ring + ((size_t)st_row[i] * NS + ttp) * 1024
                                + dir * NH + st_ch[i] * 8;
        __builtin_amdgcn_global_load_lds((gas_u32*)gp,
                                         (las_u32*)(s_h + (size_t)(i * 256 + t) * 8),
                                         16, 0, 0);
      }
      __syncthreads();   // drains DMA (vmcnt) + last step's xz/mask prefetch
      const int r = w * 16 + l16;
#pragma unroll
      for (int kt = 0; kt < 16; kt++) {
        int chunk = (kt * 4 + quad) ^ r;
        half8_t af = *(const half8_t*)(s_h + r * 512 + chunk * 8);
#pragma unroll
        for (int nt = 0; nt < 4; nt++)
          acc[nt] = __builtin_amdgcn_mfma_f32_16x16x32_f16(af, ufrag[kt][nt], acc[nt], 0, 0, 0);
      }
    }

    // gates directly in MFMA register layout; no LDS transpose.
    // acc[nt][r4] = z[row0+r4][nt*16+l16]; gate i/f/g/o == nt 0/1/2/3.
#pragma unroll
    for (int r4 = 0; r4 < 4; r4++) {
      float zi = acc[0][r4] + __half2float(xzr[0  + r4]);
      float zf = acc[1][r4] + __half2float(xzr[4  + r4]);
      float zg = acc[2][r4] + __half2float(xzr[8  + r4]);
      float zo = acc[3][r4] + __half2float(xzr[12 + r4]);
      float ig = fast_sig(zi);
      float fg = fast_sig(zf);
      float gv = fast_tanh(zg);
      float og = fast_sig(zo);
      float cn = fg * c_st[r4] + ig * gv;
      float hn = og * fast_tanh(cn);
      if (tmsk[r4] != 0) { c_st[r4] = cn; h_st[r4] = hn; }
      // plain 2B store: write-through L1 -> ack at shared home-XCD L2
      ring[((size_t)(row0 + r4) * NS + tt) * 1024 + dir * NH + hc0 + l16] =
          __float2half(h_st[r4]);
    }
    if (hT_out && s == NS - 1) {
#pragma unroll
      for (int r4 = 0; r4 < 4; r4++)
        hT_out[(size_t)(row0 + r4) * 1024 + dir * NH + hc0 + l16] = h_st[r4];
    }

    if (s < NS - 1) {
      __syncthreads();      // drains vmcnt(0): h stores ack'd at home L2;
                            // also closes s_h WAR before next staging
      if (t == 0)
        __hip_atomic_store(myflags + cblk, s + 1, __ATOMIC_RELAXED,
                           __HIP_MEMORY_SCOPE_AGENT);
      // all 4 waves poll independently (AGENT load bypasses L1; shared XCD L2
      // is single-copy -> always fresh). No release barrier needed.
      {
        int aborted = 0, it = 0;
        while (true) {
          int f = __hip_atomic_load(myflags + (lane & 31),
                                    __ATOMIC_RELAXED, __HIP_MEMORY_SCOPE_AGENT);
          if (__all(f >= s + 1)) break;
          __builtin_amdgcn_s_sleep(2);
          if (((++it) & 1023) == 0) {
            if (it > 200000)
              __hip_atomic_store(abortf, 1, __ATOMIC_RELAXED, __HIP_MEMORY_SCOPE_AGENT);
            if (__hip_atomic_load(abortf, __ATOMIC_RELAXED, __HIP_MEMORY_SCOPE_AGENT)) {
              aborted = 1; break;
            }
          }
        }
        if (aborted) return;   // wave-uniform; before any barrier -> no hang
      }
      // prefetch xz+mask(s+1): off the signal path; overlaps next staging DMA
      {
        const int ttn = dir ? (tt - 1) : (tt + 1);
        PREFETCH_NEXT(ttn);
      }
    }
  }
}

// ---------- fp32 SMEM GEMM (head only) ----------
template <int ACT>
__global__ __launch_bounds__(256) void gemm_kernel(
    const float* __restrict__ A, const float* __restrict__ W,
    const float* __restrict__ bias, float* __restrict__ C,
    int M, int N, int K) {
  __shared__ __align__(16) float As[8][128];
  __shared__ __align__(16) float Bs[8][128];
  const int t  = threadIdx.x;
  const int bn = blockIdx.x * 128;
  const int bm = blockIdx.y * 128;
  const int tx = t & 15, ty = t >> 4;
  const int lm  = t >> 1;
  const int lk4 = (t & 1) * 4;
  const int lbk = t >> 5;
  const int lbn = (t & 31) * 4;
  float acc[8][8];
#pragma unroll
  for (int i = 0; i < 8; i++)
#pragma unroll
    for (int j = 0; j < 8; j++) acc[i][j] = 0.f;

  for (int k0 = 0; k0 < K; k0 += 8) {
#pragma unroll
    for (int i = 0; i < 4; i++) {
      int k = k0 + lk4 + i;
      int m = bm + lm;
      float v = 0.f;
      if (k < K && m < M) v = A[(size_t)m * K + k];
      As[lk4 + i][lm] = v;
    }
    {
      int k = k0 + lbk;
      float4 v = make_float4(0.f, 0.f, 0.f, 0.f);
      if (k < K) v = *(const float4*)(W + (size_t)k * N + bn + lbn);
      *(float4*)(&Bs[lbk][lbn]) = v;
    }
    __syncthreads();
#pragma unroll
    for (int kk = 0; kk < 8; kk++) {
      float a[8], bb[8];
      *(float4*)(a)      = *(const float4*)(&As[kk][ty * 8]);
      *(float4*)(a + 4)  = *(const float4*)(&As[kk][ty * 8 + 4]);
      *(float4*)(bb)     = *(const float4*)(&Bs[kk][tx * 8]);
      *(float4*)(bb + 4) = *(const float4*)(&Bs[kk][tx * 8 + 4]);
#pragma unroll
      for (int i = 0; i < 8; i++)
#pragma unroll
        for (int j = 0; j < 8; j++) acc[i][j] += a[i] * bb[j];
    }
    __syncthreads();
  }
  float4 bv0 = *(const float4*)(bias + bn + tx * 8);
  float4 bv1 = *(const float4*)(bias + bn + tx * 8 + 4);
#pragma unroll
  for (int i = 0; i < 8; i++) {
    int m = bm + ty * 8 + i;
    if (m >= M) continue;
    float4 o0, o1;
    o0.x = acc[i][0] + bv0.x; o0.y = acc[i][1] + bv0.y;
    o0.z = acc[i][2] + bv0.z; o0.w = acc[i][3] + bv0.w;
    o1.x = acc[i][4] + bv1.x; o1.y = acc[i][5] + bv1.y;
    o1.z = acc[i][6] + bv1.z; o1.w = acc[i][7] + bv1.w;
    if (ACT == 1) {
      o0.x = o0.x >= 0.f ? o0.x : 0.2f * o0.x;  o0.y = o0.y >= 0.f ? o0.y : 0.2f * o0.y;
      o0.z = o0.z >= 0.f ? o0.z : 0.2f * o0.z;  o0.w = o0.w >= 0.f ? o0.w : 0.2f * o0.w;
      o1.x = o1.x >= 0.f ? o1.x : 0.2f * o1.x;  o1.y = o1.y >= 0.f ? o1.y : 0.2f * o1.y;
      o1.z = o1.z >= 0.f ? o1.z : 0.2f * o1.z;  o1.w = o1.w >= 0.f ? o1.w : 0.2f * o1.w;
    }
    *(float4*)(C + (size_t)m * N + bn + tx * 8)     = o0;
    *(float4*)(C + (size_t)m * N + bn + tx * 8 + 4) = o1;
  }
}

__global__ void final_kernel(const float* __restrict__ a1, const float* __restrict__ w,
                             const float* __restrict__ bias, float* __restrict__ out) {
  const int b = blockIdx.x, t = threadIdx.x;
  float v = a1[b * 256 + t] * w[t];
#pragma unroll
  for (int off = 32; off > 0; off >>= 1) v += __shfl_down(v, off, 64);
  __shared__ float red[4];
  if ((t & 63) == 0) red[t >> 6] = v;
  __syncthreads();
  if (t == 0) out[b] = (red[0] + red[1]) + (red[2] + red[3]) + bias[0];
}

extern "C" void kernel_launch(void* const* d_in, const int* in_sizes, int n_in,
                              void* d_out, int out_size, void* d_ws, size_t ws_size,
                              hipStream_t stream) {
  const int*   text = (const int*)  d_in[0];
  const float* emb  = (const float*)d_in[1];
  const float* W0f  = (const float*)d_in[2];
  const float* U0f  = (const float*)d_in[3];
  const float* b0f  = (const float*)d_in[4];
  const float* W0b  = (const float*)d_in[5];
  const float* U0b  = (const float*)d_in[6];
  const float* b0b  = (const float*)d_in[7];
  const float* W1f  = (const float*)d_in[8];
  const float* U1f  = (const float*)d_in[9];
  const float* b1f  = (const float*)d_in[10];
  const float* W1b  = (const float*)d_in[11];
  const float* U1b  = (const float*)d_in[12];
  const float* b1b  = (const float*)d_in[13];
  const float* d0w  = (const float*)d_in[14];
  const float* d0b  = (const float*)d_in[15];
  const float* d1w  = (const float*)d_in[16];
  const float* d1b  = (const float*)d_in[17];
  const float* d2w  = (const float*)d_in[18];
  const float* d2b  = (const float*)d_in[19];
  float* out = (float*)d_out;

  // workspace carve: identical to proven footprint (168,955,904 B)
  char* p = (char*)d_ws;
  __half* xzA = (__half*)p;  p += (size_t)NB * NS * N4H * 2;
  __half* xzB = (__half*)p;  p += (size_t)NB * NS * N4H * 2;
  char* region1 = p;         p += (size_t)NB * NS * 1024 * 2;
  _Float16* x_emb = (_Float16*)region1;   // dead before hs0 written
  __half*   hs0   = (__half*)region1;     // layer-0 ring == hs output; layer-1 ring reuses
  __half* hp0  = (__half*)p;  p += 64 * 1024 * 2;   // unused (carve kept identical)
  __half* hp1  = (__half*)p;  p += 64 * 1024 * 2;   // unused
  int*    cnt  = (int*)p;     p += 64 * 1024 * 4;   // barrier flags + abort
  float*  feat = (float*)p;   p += 64 * 1024 * 4;
  float*  a0   = (float*)p;   p += 64 * 512 * 4;
  float*  a1   = (float*)p;   p += 64 * 256 * 4;
  (void)hp0; (void)hp1;
  int* flags0 = cnt;          // layer0: [dir*32 + cblk], monotonic step count
  int* flags1 = cnt + 64;     // layer1
  int* abortf = cnt + 128;

  hipMemsetAsync(cnt, 0, 129 * sizeof(int), stream);
  hipLaunchKernelGGL(embed_f16_kernel, dim3(4096), dim3(256), 0, stream, text, emb, x_emb);

  dim3 gmf(16, 128);
  hipLaunchKernelGGL(gemm_mfma_kernel, gmf, dim3(256), 0, stream, x_emb, W0f, b0f, xzA, 16384, N4H, NDP, ND);
  hipLaunchKernelGGL(gemm_mfma_kernel, gmf, dim3(256), 0, stream, x_emb, W0b, b0b, xzB, 16384, N4H, NDP, ND);

  hipLaunchKernelGGL(scan_ring_kernel, dim3(256), dim3(256), 0, stream,
                     xzA, xzB, U0f, U0b, text, hs0, flags0, abortf, (float*)nullptr);

  hipLaunchKernelGGL(gemm_mfma_kernel, gmf, dim3(256), 0, stream, (const _Float16*)hs0, W1f, b1f, xzA, 16384, N4H, 1024, 1024);
  hipLaunchKernelGGL(gemm_mfma_kernel, gmf, dim3(256), 0, stream, (const _Float16*)hs0, W1b, b1b, xzB, 16384, N4H, 1024, 1024);

  // layer-1 ring reuses region1 (hs0 dead after the two GEMMs above)
  hipLaunchKernelGGL(scan_ring_kernel, dim3(256), dim3(256), 0, stream,
                     xzA, xzB, U1f, U1b, text, hs0, flags1, abortf, feat);

  gemm_kernel<1><<<dim3(4, 1), dim3(256), 0, stream>>>(feat, d0w, d0b, a0, 64, 512, 1024);
  gemm_kernel<1><<<dim3(2, 1), dim3(256), 0, stream>>>(a0, d1w, d1b, a1, 64, 256, 512);
  hipLaunchKernelGGL(final_kernel, dim3(64), dim3(256), 0, stream, a1, d2w, d2b, out);
}